// Round 9
// baseline (295.707 us; speedup 1.0000x reference)
//
#include <hip/hip_runtime.h>

typedef __bf16 bf16;
typedef __bf16 bf16x4 __attribute__((ext_vector_type(4)));
typedef __bf16 bf16x8 __attribute__((ext_vector_type(8)));
typedef float f32x4 __attribute__((ext_vector_type(4)));

#define BM 128
#define BN 128
#define BK 64

// ---------------------------------------------------------------- helpers
__device__ __forceinline__ float apply_epi(float v, int epi) {
  if (epi == 1) return v > 0.f ? v + 1.f : __expf(v);   // elu(v)+1
  if (epi == 2) return v >= 0.f ? v : 0.1f * v;         // leaky relu 0.1
  return v;
}

__device__ __forceinline__ void g2l16(const bf16* gp, bf16* lp) {
  __builtin_amdgcn_global_load_lds(
      (const __attribute__((address_space(1))) void*)gp,
      (__attribute__((address_space(3))) void*)lp, 16, 0, 0);
}

// ---------------------------------------------------------------- dtype detect
__global__ void detect_kernel(const unsigned* g1raw, int* flag) {
  if (threadIdx.x == 0 && blockIdx.x == 0)
    *flag = (g1raw[0] == 0x3F800000u) ? 1 : 0;
}

// ---------------------------------------------------------------- fused convert + weight transpose
struct TransArgs {
  const void* src[6];
  bf16* dst[6];
  int R[6], C[6], t0[6];
};

__global__ __launch_bounds__(256) void prep_kernel(
    const void* __restrict__ xin, const void* __restrict__ sin,
    bf16* __restrict__ bx, bf16* __restrict__ bs,
    TransArgs ta, const int* flagp) {
  const bool f32 = (*flagp != 0);
  if (blockIdx.x < 8192) {
    const void* s;
    bf16* d;
    size_t i;
    if (blockIdx.x < 4096) {
      s = xin; d = bx; i = (size_t)blockIdx.x * 2048 + threadIdx.x * 8;
    } else {
      s = sin; d = bs; i = (size_t)(blockIdx.x - 4096) * 2048 + threadIdx.x * 8;
    }
    if (f32) {
      f32x4 lo = *(const f32x4*)((const float*)s + i);
      f32x4 hi = *(const f32x4*)((const float*)s + i + 4);
      bf16x8 t;
      t[0] = (bf16)lo[0]; t[1] = (bf16)lo[1]; t[2] = (bf16)lo[2]; t[3] = (bf16)lo[3];
      t[4] = (bf16)hi[0]; t[5] = (bf16)hi[1]; t[6] = (bf16)hi[2]; t[7] = (bf16)hi[3];
      *(bf16x8*)(d + i) = t;
    } else {
      *(bf16x8*)(d + i) = *(const bf16x8*)((const bf16*)s + i);
    }
    return;
  }
  __shared__ bf16 tile[32][33];
  int bid = blockIdx.x - 8192;
  int si = 0;
#pragma unroll
  for (int i = 1; i < 6; ++i)
    if (bid >= ta.t0[i]) si = i;
  const void* srcv = ta.src[si];
  bf16* dst = ta.dst[si];
  int R = ta.R[si], Cc = ta.C[si];
  int lt = bid - ta.t0[si];
  int tpr = Cc >> 5;
  int tr = lt / tpr, tc = lt % tpr;
  int tx = threadIdx.x & 31, ty0 = threadIdx.x >> 5;
#pragma unroll
  for (int i = 0; i < 4; ++i) {
    int ty = ty0 + i * 8;
    size_t idx = (size_t)(tr * 32 + ty) * Cc + tc * 32 + tx;
    tile[ty][tx] = f32 ? (bf16)((const float*)srcv)[idx] : ((const bf16*)srcv)[idx];
  }
  __syncthreads();
#pragma unroll
  for (int i = 0; i < 4; ++i) {
    int ty = ty0 + i * 8;
    dst[(size_t)(tc * 32 + ty) * R + tr * 32 + tx] = tile[tx][ty];
  }
}

// ---------------------------------------------------------------- GEMM: C = A[M,K] @ Bt[N,K]^T, bf16 in/out
// A2: concat mode (k>=256 reads A2). C2/split: split-output mode (block-uniform).
// transC: write C^T via LDS transpose — output layout [col][32768], coalesced rows.
// Staging: linear global_load_lds (monotonic lane addresses — R7 showed permuted
// gathers defeat the coalescer; LDS bank conflicts on fragment reads are the
// lesser evil).
__global__ __launch_bounds__(256) void gemm_rt(
    const bf16* __restrict__ A, const bf16* __restrict__ A2, int ldA,
    const bf16* __restrict__ Bt, bf16* __restrict__ C, int Nn, int Kk, int epi,
    bf16* __restrict__ C2, int epi2, int split, int transC) {
  __shared__ bf16 SH[BM * BK + BN * BK];
  bf16* As = SH;
  bf16* Bs = SH + BM * BK;
  const int tid = threadIdx.x;
  const int m0 = blockIdx.x * BM;
  const int n0 = blockIdx.y * BN;
  const int wave = tid >> 6, lane = tid & 63;
  const int wm = (wave & 1) * 64, wn = (wave >> 1) * 64;
  const int q = lane >> 4, mr = lane & 15;

  f32x4 acc[4][4];
#pragma unroll
  for (int i = 0; i < 4; ++i)
#pragma unroll
    for (int j = 0; j < 4; ++j) acc[i][j] = (f32x4){0.f, 0.f, 0.f, 0.f};

  const int kTiles = Kk / BK;
  for (int kt = 0; kt < kTiles; ++kt) {
    int kk = kt * BK;
    const bf16* Ab = A;
    int kcol = kk;
    if (A2 && kk >= 256) { Ab = A2; kcol = kk - 256; }
    __syncthreads();
#pragma unroll
    for (int it = 0; it < 4; ++it) {
      int id = it * 256 + tid;
      int rr = id >> 3, pp = id & 7;
      g2l16(Ab + (size_t)(m0 + rr) * ldA + kcol + pp * 8, &As[id * 8]);
    }
#pragma unroll
    for (int it = 0; it < 4; ++it) {
      int id = it * 256 + tid;
      int rr = id >> 3, pp = id & 7;
      g2l16(Bt + (size_t)(n0 + rr) * Kk + kk + pp * 8, &Bs[id * 8]);
    }
    __syncthreads();
#pragma unroll
    for (int ks = 0; ks < 2; ++ks) {
      bf16x8 af[4], bfv[4];
#pragma unroll
      for (int mi = 0; mi < 4; ++mi)
        af[mi] = *(const bf16x8*)&As[(wm + mi * 16 + mr) * BK + (ks * 4 + q) * 8];
#pragma unroll
      for (int ni = 0; ni < 4; ++ni)
        bfv[ni] = *(const bf16x8*)&Bs[(wn + ni * 16 + mr) * BK + (ks * 4 + q) * 8];
#pragma unroll
      for (int mi = 0; mi < 4; ++mi)
#pragma unroll
        for (int ni = 0; ni < 4; ++ni)
          acc[mi][ni] = __builtin_amdgcn_mfma_f32_16x16x32_bf16(af[mi], bfv[ni], acc[mi][ni], 0, 0, 0);
    }
  }

  if (transC) {
    // write transposed: out[col_glob][32768], via LDS T[64][136] in 2 passes
    bf16* TC = C;
    int cb = n0, ep = epi;
    if (C2 && n0 >= split) { TC = C2; cb = n0 - split; ep = epi2; }
#pragma unroll
    for (int p = 0; p < 2; ++p) {
      __syncthreads();
      if ((wave >> 1) == p) {
#pragma unroll
        for (int mi = 0; mi < 4; ++mi)
#pragma unroll
          for (int ni = 0; ni < 4; ++ni)
#pragma unroll
            for (int r4 = 0; r4 < 4; ++r4) {
              int cl = ni * 16 + mr;               // 0..63 within pass
              int sl = wm + mi * 16 + q * 4 + r4;  // 0..127
              SH[cl * 136 + sl] = (bf16)apply_epi(acc[mi][ni][r4], ep);
            }
      }
      __syncthreads();
      int row = tid >> 2, c0 = (tid & 3) * 32;
      size_t gbase = (size_t)(cb + p * 64 + row) * 32768 + m0 + c0;
#pragma unroll
      for (int j = 0; j < 4; ++j)
        *(bf16x8*)(TC + gbase + j * 8) = *(const bf16x8*)&SH[row * 136 + c0 + j * 8];
    }
    return;
  }

  bf16* Cw = C;
  int nbase = n0, ep = epi;
  if (C2 && n0 >= split) { Cw = C2; nbase = n0 - split; ep = epi2; }
#pragma unroll
  for (int mi = 0; mi < 4; ++mi)
#pragma unroll
    for (int ni = 0; ni < 4; ++ni)
#pragma unroll
      for (int r4 = 0; r4 < 4; ++r4) {
        int row = m0 + wm + mi * 16 + q * 4 + r4;
        int cn = nbase + wn + ni * 16 + mr;
        float v = apply_epi(acc[mi][ni][r4], ep);
        Cw[(size_t)row * Nn + cn] = (bf16)v;
      }
}

// ---------------------------------------------------------------- KV via MFMA (split-K partials)
// Kt/Vt: [256 rows = h*32+d][32768 cols = n*8192+s]. Block (sk,h,n) does a
// 32x32 tile over k = 256 s-positions (32 chunks x 256 = 8192 per batch),
// 4 waves = 4 16x16 tiles, VGPR-staged padded LDS.
#define KSK 256
#define KLD 264  // LDS stride: 528 B -> rotates banks per row -> conflict-light
__global__ __launch_bounds__(256) void kv_mfma(
    const bf16* __restrict__ Kt, const bf16* __restrict__ Vt,
    float* __restrict__ partial, float* __restrict__ pk) {
  __shared__ bf16 As[32 * KLD];
  __shared__ bf16 Bs[32 * KLD];
  __shared__ float ksl[32][8];
  const int sk = blockIdx.x, h = blockIdx.y, n = blockIdx.z;
  const int tid = threadIdx.x;
  const int wave = tid >> 6, lane = tid & 63;
  const int q = lane >> 4, mr = lane & 15;
  const int mh = wave & 1, nh = wave >> 1;
  const size_t colBase = (size_t)n * 8192 + (size_t)sk * KSK;  // sk*256 < 8192
  const bf16* Ab = Kt + (size_t)(h * 32) * 32768 + colBase;
  const bf16* Bb = Vt + (size_t)(h * 32) * 32768 + colBase;
  const int lrow = tid >> 3, lch = (tid & 7) * 32;
  f32x4 acc = {0.f, 0.f, 0.f, 0.f};
  float kreg = 0.f;
  bf16x8 a4[4], b4[4];
#pragma unroll
  for (int j = 0; j < 4; ++j) {
    a4[j] = *(const bf16x8*)(Ab + (size_t)lrow * 32768 + lch + j * 8);
    b4[j] = *(const bf16x8*)(Bb + (size_t)lrow * 32768 + lch + j * 8);
  }
#pragma unroll
  for (int j = 0; j < 4; ++j) {
    *(bf16x8*)&As[lrow * KLD + lch + j * 8] = a4[j];
    *(bf16x8*)&Bs[lrow * KLD + lch + j * 8] = b4[j];
  }
  __syncthreads();
#pragma unroll
  for (int kk = 0; kk < KSK; kk += 32) {
    bf16x8 af = *(const bf16x8*)&As[(mh * 16 + mr) * KLD + kk + q * 8];
    bf16x8 bf = *(const bf16x8*)&Bs[(nh * 16 + mr) * KLD + kk + q * 8];
    acc = __builtin_amdgcn_mfma_f32_16x16x32_bf16(af, bf, acc, 0, 0, 0);
  }
  // ksum partial from staged K tile
#pragma unroll
  for (int j = 0; j < 4; ++j) {
    bf16x8 kx = *(const bf16x8*)&As[lrow * KLD + lch + j * 8];
#pragma unroll
    for (int e = 0; e < 8; ++e) kreg += (float)kx[e];
  }
  const size_t slot = (size_t)(n * 8 + h) * 32 + sk;
  // C[m=d][n=dv]; partial layout [dv][d]
#pragma unroll
  for (int r = 0; r < 4; ++r) {
    int d = mh * 16 + q * 4 + r, dv = nh * 16 + mr;
    partial[slot * 1024 + (size_t)dv * 32 + d] = acc[r];
  }
  ksl[lrow][tid & 7] = kreg;
  __syncthreads();
  if (tid < 32) {
    float ss = 0.f;
#pragma unroll
    for (int e = 0; e < 8; ++e) ss += ksl[tid][e];
    pk[slot * 32 + tid] = ss;
  }
}

// ---------------------------------------------------------------- reduce partials -> kv_acc, ksum
__global__ __launch_bounds__(256) void kv_reduce(
    const float* __restrict__ partial, const float* __restrict__ pk,
    float* __restrict__ kv_acc, float* __restrict__ ksum) {
  const int b = blockIdx.x;  // n*8+h
  const int t = threadIdx.x;
  f32x4 s4 = {0.f, 0.f, 0.f, 0.f};
  for (int c = 0; c < 32; ++c)
    s4 += *(const f32x4*)&partial[((size_t)b * 32 + c) * 1024 + t * 4];
  *(f32x4*)&kv_acc[(size_t)b * 1024 + t * 4] = s4;
  if (t < 32) {
    float ss = 0.f;
    for (int c = 0; c < 32; ++c) ss += pk[((size_t)b * 32 + c) * 32 + t];
    ksum[(size_t)b * 32 + t] = ss;
  }
}

// ---------------------------------------------------------------- msg = (Q @ KV) * z  per head
__global__ __launch_bounds__(256) void msg_kernel(
    const bf16* __restrict__ Q, const float* __restrict__ kv_acc,
    const float* __restrict__ ksum, bf16* __restrict__ msg) {
  __shared__ bf16 kvt[8][32][32];  // [h][dv][d]
  __shared__ float ksl[8][32];
  __shared__ float zl[8][128];
  int tid = threadIdx.x;
  int row0 = blockIdx.x * 128;
  int n = row0 >> 13;
  const float* kvb = kv_acc + (size_t)n * 8192;
  for (int i = tid; i < 8192; i += 256) ((bf16*)kvt)[i] = (bf16)kvb[i];
  ((float*)ksl)[tid] = ksum[(size_t)n * 256 + tid];
  __syncthreads();
  int r = tid & 127, hg = tid >> 7;
  const bf16* qrow = Q + (size_t)(row0 + r) * 256;
#pragma unroll
  for (int hh = 0; hh < 4; ++hh) {
    int h = hg * 4 + hh;
    float dot = 0.f;
#pragma unroll
    for (int d = 0; d < 32; ++d) dot = fmaf((float)qrow[h * 32 + d], ksl[h][d], dot);
    zl[h][r] = 1.f / (dot + 1e-6f);
  }
  __syncthreads();
  int wave = tid >> 6, lane = tid & 63, q = lane >> 4, mr = lane & 15;
  f32x4 zero = {0.f, 0.f, 0.f, 0.f};
  for (int h = 0; h < 8; ++h) {
    bf16x8 b0 = *(const bf16x8*)&kvt[h][mr][q * 8];
    bf16x8 b1 = *(const bf16x8*)&kvt[h][16 + mr][q * 8];
#pragma unroll
    for (int mi = 0; mi < 2; ++mi) {
      int arow = wave * 32 + mi * 16 + mr;
      bf16x8 a = *(const bf16x8*)(Q + (size_t)(row0 + arow) * 256 + h * 32 + q * 8);
      f32x4 c0 = __builtin_amdgcn_mfma_f32_16x16x32_bf16(a, b0, zero, 0, 0, 0);
      f32x4 c1 = __builtin_amdgcn_mfma_f32_16x16x32_bf16(a, b1, zero, 0, 0, 0);
#pragma unroll
      for (int r4 = 0; r4 < 4; ++r4) {
        int orow = wave * 32 + mi * 16 + q * 4 + r4;
        float z = zl[h][orow];
        size_t ob = (size_t)(row0 + orow) * 256 + h * 32;
        msg[ob + mr] = (bf16)(c0[r4] * z);
        msg[ob + 16 + mr] = (bf16)(c1[r4] * z);
      }
    }
  }
}

// ---------------------------------------------------------------- LayerNorm (+optional residual)
__global__ __launch_bounds__(256) void ln_kernel(
    const bf16* __restrict__ in, const void* __restrict__ g, const void* __restrict__ b,
    const void* __restrict__ resid, void* __restrict__ outp,
    const int* flagp, int ioDual) {
  const bool gbF32 = (*flagp != 0);
  const bool ioF32 = ioDual && gbF32;
  int wave = threadIdx.x >> 6, lane = threadIdx.x & 63;
  size_t row = (size_t)blockIdx.x * 4 + wave;
  int c = lane * 4;
  bf16x4 v = *(const bf16x4*)(in + row * 256 + c);
  float x0 = (float)v[0], x1 = (float)v[1], x2 = (float)v[2], x3 = (float)v[3];
  float s = x0 + x1 + x2 + x3;
  float sq = x0 * x0 + x1 * x1 + x2 * x2 + x3 * x3;
#pragma unroll
  for (int o = 32; o > 0; o >>= 1) {
    s += __shfl_xor(s, o);
    sq += __shfl_xor(sq, o);
  }
  float mean = s * (1.f / 256.f);
  float var = sq * (1.f / 256.f) - mean * mean;
  float rstd = rsqrtf(var + 1e-5f);
  float g0, g1v, g2v, g3, b0, b1v, b2v, b3;
  if (gbF32) {
    f32x4 gv = *(const f32x4*)((const float*)g + c);
    f32x4 bv = *(const f32x4*)((const float*)b + c);
    g0 = gv[0]; g1v = gv[1]; g2v = gv[2]; g3 = gv[3];
    b0 = bv[0]; b1v = bv[1]; b2v = bv[2]; b3 = bv[3];
  } else {
    bf16x4 gv = *(const bf16x4*)((const bf16*)g + c);
    bf16x4 bv = *(const bf16x4*)((const bf16*)b + c);
    g0 = (float)gv[0]; g1v = (float)gv[1]; g2v = (float)gv[2]; g3 = (float)gv[3];
    b0 = (float)bv[0]; b1v = (float)bv[1]; b2v = (float)bv[2]; b3 = (float)bv[3];
  }
  float y0 = (x0 - mean) * rstd * g0 + b0;
  float y1 = (x1 - mean) * rstd * g1v + b1v;
  float y2 = (x2 - mean) * rstd * g2v + b2v;
  float y3 = (x3 - mean) * rstd * g3 + b3;
  if (resid) {
    if (ioF32) {
      f32x4 rv = *(const f32x4*)((const float*)resid + row * 256 + c);
      y0 += rv[0]; y1 += rv[1]; y2 += rv[2]; y3 += rv[3];
    } else {
      bf16x4 rv = *(const bf16x4*)((const bf16*)resid + row * 256 + c);
      y0 += (float)rv[0]; y1 += (float)rv[1]; y2 += (float)rv[2]; y3 += (float)rv[3];
    }
  }
  if (ioF32) {
    f32x4 o4 = {y0, y1, y2, y3};
    *(f32x4*)((float*)outp + row * 256 + c) = o4;
  } else {
    bf16x4 o4;
    o4[0] = (bf16)y0; o4[1] = (bf16)y1; o4[2] = (bf16)y2; o4[3] = (bf16)y3;
    *(bf16x4*)((bf16*)outp + row * 256 + c) = o4;
  }
}

// ---------------------------------------------------------------- launch
extern "C" void kernel_launch(void* const* d_in, const int* in_sizes, int n_in,
                              void* d_out, int out_size, void* d_ws, size_t ws_size,
                              hipStream_t stream) {
  const void* x   = d_in[0];
  const void* src = d_in[1];
  const void* Wq  = d_in[2];
  const void* Wk  = d_in[3];
  const void* Wv  = d_in[4];
  const void* Wm  = d_in[5];
  const void* W1  = d_in[6];
  const void* W2  = d_in[7];
  const void* g1  = d_in[8];
  const void* b1  = d_in[9];
  const void* g2  = d_in[10];
  const void* b2  = d_in[11];

  char* ws = (char*)d_ws;
  bf16* bufA = (bf16*)(ws);                       // 16 MiB (Q)
  bf16* bufB = (bf16*)(ws + ((size_t)16 << 20));  // 16 MiB (Kt [256][32768], later msg)
  bf16* bufC = (bf16*)(ws + ((size_t)32 << 20));  // 16 MiB (Vt [256][32768], later m1ln/m2pre)
  bf16* WqT  = (bf16*)(ws + ((size_t)48 << 20));
  bf16* WkvT = WqT + 65536;   // [512][256]: rows 0-255 Wk^T, 256-511 Wv^T
  bf16* WmT  = WkvT + 131072;
  bf16* W1T  = WmT + 65536;   // 262144 elems
  bf16* W2T  = W1T + 262144;  // 131072 elems
  float* kv_acc = (float*)(ws + ((size_t)50 << 20));  // 32768 f32
  float* ksum = kv_acc + 32768;                       // 1024 f32
  int* flagp = (int*)(ws + ((size_t)50 << 20) + 160 * 1024);
  float* partial = (float*)(ws + ((size_t)51 << 20));  // 1024 x 1024 f32 = 4 MiB
  float* pk = (float*)(ws + ((size_t)55 << 20));       // 1024 x 32 f32
  bf16* bufX = (bf16*)d_out;       // bf16 x in d_out (rewritten by final LN)
  bf16* bufS = bufX + 8388608;

  // 0. dtype detect
  detect_kernel<<<dim3(1), dim3(64), 0, stream>>>((const unsigned*)g1, flagp);

  // 1. fused convert + weight transpose
  TransArgs ta;
  ta.src[0] = Wq; ta.src[1] = Wk; ta.src[2] = Wv; ta.src[3] = Wm; ta.src[4] = W1; ta.src[5] = W2;
  ta.dst[0] = WqT; ta.dst[1] = WkvT; ta.dst[2] = WkvT + 65536; ta.dst[3] = WmT; ta.dst[4] = W1T; ta.dst[5] = W2T;
  ta.R[0] = 256; ta.R[1] = 256; ta.R[2] = 256; ta.R[3] = 256; ta.R[4] = 512; ta.R[5] = 512;
  ta.C[0] = 256; ta.C[1] = 256; ta.C[2] = 256; ta.C[3] = 256; ta.C[4] = 512; ta.C[5] = 256;
  ta.t0[0] = 0; ta.t0[1] = 64; ta.t0[2] = 128; ta.t0[3] = 192; ta.t0[4] = 256; ta.t0[5] = 512;
  prep_kernel<<<dim3(8832), dim3(256), 0, stream>>>(x, src, bufX, bufS, ta, flagp);

  // 2. Q = feat(x@Wq) -> bufA
  gemm_rt<<<dim3(256, 2), dim3(256), 0, stream>>>(bufX, nullptr, 256, WqT, bufA, 256, 256, 1,
                                                  nullptr, 0, 0, 0);
  // 3. Kt = feat(src@Wk)^T -> bufB  |  Vt = (src@Wv)^T -> bufC  (transposed epilogue)
  gemm_rt<<<dim3(256, 4), dim3(256), 0, stream>>>(bufS, nullptr, 256, WkvT, bufB, 256, 256, 1,
                                                  bufC, 0, 256, 1);

  // 4. KV/Ksum partials via MFMA + 5. reduce
  kv_mfma<<<dim3(32, 8, 4), dim3(256), 0, stream>>>(bufB, bufC, partial, pk);
  kv_reduce<<<dim3(32), dim3(256), 0, stream>>>(partial, pk, kv_acc, ksum);

  // 6. msg_pre -> bufB
  msg_kernel<<<dim3(256), dim3(256), 0, stream>>>(bufA, kv_acc, ksum, bufB);

  // 7. m1pre = msg_pre @ Wm -> bufA
  gemm_rt<<<dim3(256, 2), dim3(256), 0, stream>>>(bufB, nullptr, 256, WmT, bufA, 256, 256, 0,
                                                  nullptr, 0, 0, 0);

  // 8. m1ln = LN(m1pre; g1,b1) -> bufC
  ln_kernel<<<dim3(8192), dim3(256), 0, stream>>>(bufA, g1, b1, nullptr, bufC, flagp, 0);

  // 9. h = leaky([x | m1ln] @ W1) -> bufA..bufB (32 MiB span)
  gemm_rt<<<dim3(256, 4), dim3(256), 0, stream>>>(bufX, bufC, 256, W1T, bufA, 512, 512, 2,
                                                  nullptr, 0, 0, 0);

  // 10. m2pre = h @ W2 -> bufC
  gemm_rt<<<dim3(256, 2), dim3(256), 0, stream>>>(bufA, nullptr, 512, W2T, bufC, 256, 512, 0,
                                                  nullptr, 0, 0, 0);

  // 11. out = x + LN(m2pre; g2,b2)
  ln_kernel<<<dim3(8192), dim3(256), 0, stream>>>(bufC, g2, b2, x, d_out, flagp, 1);
}